// Round 1
// baseline (5614.323 us; speedup 1.0000x reference)
//
#include <hip/hip_runtime.h>
#include <hip/hip_bf16.h>
#include <cstdint>

typedef unsigned short u16;
typedef __attribute__((ext_vector_type(8))) short short8;   // 8 bf16 (4 VGPRs) MFMA A/B frag
typedef __attribute__((ext_vector_type(4))) float floatx4;  // MFMA C/D frag

#define Bn 256
#define Pn 256
#define ENCn 256
#define DECn 512
#define En 256
#define Vn 5000
#define Tn 96

#define PRED_SZ 122880000   // 256*96*5000
#define LEN_OFF 122880000
#define ALPHA_OFF 122880256

__device__ __forceinline__ u16 f2bf(float x) {
  unsigned u = __float_as_uint(x);
  u += 0x7FFFu + ((u >> 16) & 1u);
  return (u16)(u >> 16);
}
__device__ __forceinline__ float bf2f(u16 h) {
  return __uint_as_float(((unsigned)h) << 16);
}
__device__ __forceinline__ float sigm(float x) { return 1.f / (1.f + __expf(-x)); }

// ---------------------------------------------------------------------------
// cast encoder_out (fp32) -> bf16
__global__ __launch_bounds__(256) void cast_k(const float* __restrict__ in, u16* __restrict__ outp) {
  int stride = gridDim.x * blockDim.x;
  for (int i = blockIdx.x * blockDim.x + threadIdx.x; i < 4194304; i += stride) {
    float4 v = ((const float4*)in)[i];
    ushort4 o;
    o.x = f2bf(v.x); o.y = f2bf(v.y); o.z = f2bf(v.z); o.w = f2bf(v.w);
    ((ushort4*)outp)[i] = o;
  }
}

// ---------------------------------------------------------------------------
// one-shot weight prep: transposed bf16 weight buffers + bias concat + lengths out
__global__ __launch_bounds__(256) void prep_k(
    const float* __restrict__ eaw, const float* __restrict__ wih, const float* __restrict__ whh,
    const float* __restrict__ daw, const float* __restrict__ fbw, const float* __restrict__ fcw,
    const float* __restrict__ bih, const float* __restrict__ bhh,
    const float* __restrict__ dab, const float* __restrict__ fbb, const float* __restrict__ fcb,
    const int* __restrict__ lens,
    u16* __restrict__ ea_t, u16* __restrict__ wcat, u16* __restrict__ wag, u16* __restrict__ wfc,
    float* __restrict__ bsum, float* __restrict__ bias_ag, float* __restrict__ bias_fc,
    float* __restrict__ outbuf) {
  long idx = (long)blockIdx.x * 256 + threadIdx.x;
  if (idx < 131072) {             // ea_t [512 n][256 k] = enc_att_w[k][n]
    int n = idx >> 8, k = idx & 255;
    ea_t[idx] = f2bf(eaw[k * 512 + n]);
    return;
  }
  idx -= 131072;
  if (idx < 2097152) {            // wcat [2048 n-interleaved][1024 k]
    int n = idx >> 10, k = idx & 1023;
    int c = (n & 3) * 512 + (n >> 2);           // gate-major orig col
    float v = (k < 512) ? wih[k * 2048 + c] : whh[(k - 512) * 2048 + c];
    wcat[idx] = f2bf(v);
    return;
  }
  idx -= 2097152;
  if (idx < 393216) {             // wag [768 n][512 k] = [dec_att_w | f_beta_w]^T
    int n = idx >> 9, k = idx & 511;
    float v = (n < 512) ? daw[k * 512 + n] : fbw[k * 256 + (n - 512)];
    wag[idx] = f2bf(v);
    return;
  }
  idx -= 393216;
  if (idx < 2588672) {            // wfc [5056 n][512 k] = fc_w^T (pad cols 5000..5055)
    int n = idx >> 9, k = idx & 511;
    float v = (n < 5000) ? fcw[k * 5000 + n] : 0.f;
    wfc[idx] = f2bf(v);
    return;
  }
  idx -= 2588672;
  if (idx < 2048) {               // bsum interleaved
    int n = (int)idx;
    int c = (n & 3) * 512 + (n >> 2);
    bsum[n] = bih[c] + bhh[c];
    return;
  }
  idx -= 2048;
  if (idx < 768) {
    bias_ag[idx] = (idx < 512) ? dab[idx] : fbb[idx - 512];
    return;
  }
  idx -= 768;
  if (idx < 5056) {
    bias_fc[idx] = (idx < 5000) ? fcb[idx] : 0.f;
    return;
  }
  idx -= 5056;
  if (idx < 256) {                // caption_lengths as float into d_out
    outbuf[LEN_OFF + idx] = (float)lens[idx];
  }
}

// ---------------------------------------------------------------------------
// S1: mean_enc -> h0 (bf16 into xh h-half), c0 (fp32). One block per b.
__global__ __launch_bounds__(256) void s1_k(
    const float* __restrict__ enc, const float* __restrict__ ihw, const float* __restrict__ ihb,
    const float* __restrict__ icw, const float* __restrict__ icb,
    u16* __restrict__ xh, float* __restrict__ cstate) {
  int b = blockIdx.x, tid = threadIdx.x;
  __shared__ float m[256];
  float s = 0.f;
  for (int p = 0; p < 256; p++) s += enc[b * 65536 + p * 256 + tid];
  m[tid] = s * (1.f / 256.f);
  __syncthreads();
  for (int h = 0; h < 2; h++) {
    int d = tid + h * 256;
    float hv = ihb[d], cv = icb[d];
    for (int e = 0; e < 256; e++) {
      float me = m[e];
      hv += me * ihw[e * 512 + d];
      cv += me * icw[e * 512 + d];
    }
    xh[b * 1024 + 512 + d] = f2bf(hv);
    cstate[b * 512 + d] = cv;
  }
}

// ---------------------------------------------------------------------------
// Generic 64x64-tile bf16 MFMA GEMM, A [M x K] row-major bf16, Bt [N x K] row-major bf16.
// mode 0: out_bf = bf16(acc+bias), ld 512 (att1 precompute)
// mode 1: cols<512 -> att2 fp32; cols 512..767 -> gate = sigmoid
// mode 2: preds epilogue with per-row (b,t) active mask; all-masked tile fast path
// mode 3: fused LSTM pointwise epilogue (interleaved gate columns)
__global__ __launch_bounds__(256) void gemm_k(
    const u16* __restrict__ A, int ldA,
    const u16* __restrict__ Bt, int K,
    const float* __restrict__ bias,
    int mode, int t,
    u16* __restrict__ out_bf,
    float* __restrict__ att2, float* __restrict__ gatebuf,
    float* __restrict__ preds, const int* __restrict__ lens,
    float* __restrict__ cstate, u16* __restrict__ xh, u16* __restrict__ hall) {
  __shared__ u16 As[64 * 32];
  __shared__ u16 Bs[64 * 32];
  __shared__ float cs[64 * 65];
  int tid = threadIdx.x;
  int n0 = blockIdx.x * 64, m0 = blockIdx.y * 64;

  if (mode == 2) {  // skip K-loop entirely for fully-masked row tiles; still write zeros
    int row = m0 + (tid & 63);
    int bb = row / 96, tt = row - bb * 96;
    int act = (tt < lens[bb]);
    if (!__syncthreads_or(act)) {
      for (int i = 0; i < 16; i++) {
        int idx = i * 256 + tid;
        int r = idx >> 6, col = n0 + (idx & 63);
        if (col < Vn) preds[(m0 + r) * Vn + col] = 0.f;
      }
      return;
    }
  }

  int lane = tid & 63, wave = tid >> 6;
  int l15 = lane & 15, q = lane >> 4;
  int ar = tid >> 2, ac = (tid & 3) * 8;
  floatx4 acc[4];
  #pragma unroll
  for (int i = 0; i < 4; i++) acc[i] = (floatx4){0.f, 0.f, 0.f, 0.f};

  const u16* Aptr = A + (long)(m0 + ar) * ldA + ac;
  const u16* Bptr = Bt + (long)(n0 + ar) * K + ac;
  for (int k0 = 0; k0 < K; k0 += 32) {
    *(uint4*)(&As[ar * 32 + ac]) = *(const uint4*)(Aptr + k0);
    *(uint4*)(&Bs[ar * 32 + ac]) = *(const uint4*)(Bptr + k0);
    __syncthreads();
    short8 bfrag = *(const short8*)(&Bs[(wave * 16 + l15) * 32 + q * 8]);
    #pragma unroll
    for (int mt = 0; mt < 4; mt++) {
      short8 afrag = *(const short8*)(&As[(mt * 16 + l15) * 32 + q * 8]);
      acc[mt] = __builtin_amdgcn_mfma_f32_16x16x32_bf16(afrag, bfrag, acc[mt], 0, 0, 0);
    }
    __syncthreads();
  }

  int col = n0 + wave * 16 + l15;
  float bv = bias[col];
  if (mode == 0) {
    #pragma unroll
    for (int mt = 0; mt < 4; mt++)
      #pragma unroll
      for (int r = 0; r < 4; r++) {
        int row = m0 + mt * 16 + q * 4 + r;
        out_bf[(long)row * 512 + col] = f2bf(acc[mt][r] + bv);
      }
  } else if (mode == 1) {
    #pragma unroll
    for (int mt = 0; mt < 4; mt++)
      #pragma unroll
      for (int r = 0; r < 4; r++) {
        int row = m0 + mt * 16 + q * 4 + r;
        float v = acc[mt][r] + bv;
        if (col < 512) att2[row * 512 + col] = v;
        else gatebuf[row * 256 + (col - 512)] = sigm(v);
      }
  } else if (mode == 2) {
    if (col < Vn) {
      #pragma unroll
      for (int mt = 0; mt < 4; mt++)
        #pragma unroll
        for (int r = 0; r < 4; r++) {
          int row = m0 + mt * 16 + q * 4 + r;
          int bb = row / 96, tt = row - bb * 96;
          float v = (tt < lens[bb]) ? (acc[mt][r] + bv) : 0.f;
          preds[(long)row * Vn + col] = v;
        }
    }
  } else {  // mode 3: LSTM pointwise via LDS round-trip
    #pragma unroll
    for (int mt = 0; mt < 4; mt++)
      #pragma unroll
      for (int r = 0; r < 4; r++)
        cs[(mt * 16 + q * 4 + r) * 65 + wave * 16 + l15] = acc[mt][r];
    __syncthreads();
    #pragma unroll
    for (int i = 0; i < 4; i++) {
      int idx = i * 256 + tid;
      int row = idx >> 4, dl = idx & 15;
      int b = m0 + row;
      int d = (n0 >> 2) + dl;
      float p0 = cs[row * 65 + dl * 4 + 0] + bias[n0 + dl * 4 + 0];
      float p1 = cs[row * 65 + dl * 4 + 1] + bias[n0 + dl * 4 + 1];
      float p2 = cs[row * 65 + dl * 4 + 2] + bias[n0 + dl * 4 + 2];
      float p3 = cs[row * 65 + dl * 4 + 3] + bias[n0 + dl * 4 + 3];
      float ig = sigm(p0), fg = sigm(p1), gg = tanhf(p2), og = sigm(p3);
      float cold = cstate[b * 512 + d];
      float cn = fg * cold + ig * gg;
      float hn = og * tanhf(cn);
      cstate[b * 512 + d] = cn;
      u16 hb = f2bf(hn);
      xh[b * 1024 + 512 + d] = hb;
      hall[(long)(b * 96 + t) * 512 + d] = hb;
    }
  }
}

// ---------------------------------------------------------------------------
// KA: per-b attention: e = fa . relu(att1[b]+att2[b]) ; softmax ; awe ; build x half of xh.
__global__ __launch_bounds__(1024) void ka_k(
    const u16* __restrict__ att1, const u16* __restrict__ encb,
    const float* __restrict__ att2, const float* __restrict__ gate,
    const float* __restrict__ fa,
    const int* __restrict__ caps, const int* __restrict__ lens,
    const float* __restrict__ embw,
    u16* __restrict__ xh, float* __restrict__ out_alphas, int t) {
  int b = blockIdx.x, tid = threadIdx.x;
  __shared__ float s_att2[512], s_fa[512], s_gate[256], part[1024], s_red[8], s_alpha[256];
  if (tid < 512) s_att2[tid] = att2[b * 512 + tid];
  else s_fa[tid - 512] = fa[tid - 512];
  if (tid < 256) s_gate[tid] = gate[b * 256 + tid];
  __syncthreads();

  // e partial dot: p = tid>>2, quarter kq = tid&3 (128 k each)
  {
    int p = tid >> 2, kq = tid & 3;
    const u16* arow = att1 + (long)(b * 256 + p) * 512 + kq * 128;
    float a = 0.f;
    #pragma unroll 4
    for (int j = 0; j < 128; j += 8) {
      short8 v = *(const short8*)(arow + j);
      floatx4 t0 = *(const floatx4*)(&s_att2[kq * 128 + j]);
      floatx4 t1 = *(const floatx4*)(&s_att2[kq * 128 + j + 4]);
      floatx4 f0 = *(const floatx4*)(&s_fa[kq * 128 + j]);
      floatx4 f1 = *(const floatx4*)(&s_fa[kq * 128 + j + 4]);
      a += fmaxf(bf2f((u16)v[0]) + t0[0], 0.f) * f0[0];
      a += fmaxf(bf2f((u16)v[1]) + t0[1], 0.f) * f0[1];
      a += fmaxf(bf2f((u16)v[2]) + t0[2], 0.f) * f0[2];
      a += fmaxf(bf2f((u16)v[3]) + t0[3], 0.f) * f0[3];
      a += fmaxf(bf2f((u16)v[4]) + t1[0], 0.f) * f1[0];
      a += fmaxf(bf2f((u16)v[5]) + t1[1], 0.f) * f1[1];
      a += fmaxf(bf2f((u16)v[6]) + t1[2], 0.f) * f1[2];
      a += fmaxf(bf2f((u16)v[7]) + t1[3], 0.f) * f1[3];
    }
    part[tid] = a;
  }
  __syncthreads();

  float e = 0.f;
  int wv = tid >> 6, ln = tid & 63;
  if (tid < 256) {
    e = part[tid * 4] + part[tid * 4 + 1] + part[tid * 4 + 2] + part[tid * 4 + 3];
    float m = e;
    for (int off = 32; off >= 1; off >>= 1) m = fmaxf(m, __shfl_xor(m, off));
    if (ln == 0) s_red[wv] = m;
  }
  __syncthreads();
  float M = fmaxf(fmaxf(s_red[0], s_red[1]), fmaxf(s_red[2], s_red[3]));
  float ex = 0.f;
  if (tid < 256) {
    ex = __expf(e - M);
    float s = ex;
    for (int off = 32; off >= 1; off >>= 1) s += __shfl_xor(s, off);
    if (ln == 0) s_red[4 + wv] = s;
  }
  __syncthreads();
  float denom = s_red[4] + s_red[5] + s_red[6] + s_red[7];
  if (tid < 256) {
    float a = ex / denom;
    s_alpha[tid] = a;
    int act = (lens[b] > t);
    out_alphas[b * (Tn * Pn) + t * Pn + tid] = act ? a : 0.f;
  }
  __syncthreads();

  // awe partials: e' = tid&255, p-chunk ph = tid>>8 (64 p each)
  {
    int eidx = tid & 255, ph = tid >> 8;
    const u16* ecol = encb + (long)b * 65536 + ph * 64 * 256 + eidx;
    float aw = 0.f;
    #pragma unroll 4
    for (int pp = 0; pp < 64; pp++)
      aw += s_alpha[ph * 64 + pp] * bf2f(ecol[pp * 256]);
    part[tid] = aw;
  }
  __syncthreads();
  if (tid < 256) {
    float awe = part[tid] + part[tid + 256] + part[tid + 512] + part[tid + 768];
    xh[b * 1024 + 256 + tid] = f2bf(s_gate[tid] * awe);
  } else if (tid < 512) {
    int j = tid - 256;
    int cap = caps[b * Tn + t];
    xh[b * 1024 + j] = f2bf(embw[cap * 256 + j]);
  }
}

// ---------------------------------------------------------------------------
extern "C" void kernel_launch(void* const* d_in, const int* in_sizes, int n_in,
                              void* d_out, int out_size, void* d_ws, size_t ws_size,
                              hipStream_t stream) {
  const float* enc  = (const float*)d_in[0];
  const int*   caps = (const int*)d_in[1];
  const int*   lens = (const int*)d_in[2];
  const float* embw = (const float*)d_in[3];
  const float* eaw  = (const float*)d_in[4];
  const float* eab  = (const float*)d_in[5];
  const float* daw  = (const float*)d_in[6];
  const float* dab  = (const float*)d_in[7];
  const float* faw  = (const float*)d_in[8];
  const float* wih  = (const float*)d_in[10];
  const float* whh  = (const float*)d_in[11];
  const float* bih  = (const float*)d_in[12];
  const float* bhh  = (const float*)d_in[13];
  const float* ihw  = (const float*)d_in[14];
  const float* ihb  = (const float*)d_in[15];
  const float* icw  = (const float*)d_in[16];
  const float* icb  = (const float*)d_in[17];
  const float* fbw  = (const float*)d_in[18];
  const float* fbb  = (const float*)d_in[19];
  const float* fcw  = (const float*)d_in[20];
  const float* fcb  = (const float*)d_in[21];
  float* out = (float*)d_out;
  char* ws = (char*)d_ws;

  u16*   att1    = (u16*)(ws + 0);            // 67,108,864 B
  u16*   encb    = (u16*)(ws + 67108864);     // 33,554,432
  u16*   wcat    = (u16*)(ws + 100663296);    //  4,194,304
  u16*   wag     = (u16*)(ws + 104857600);    //    786,432
  u16*   wfc     = (u16*)(ws + 105644032);    //  5,177,344
  u16*   hall    = (u16*)(ws + 110821376);    // 25,165,824
  u16*   ea_t    = (u16*)(ws + 135987200);    //    262,144
  u16*   xh      = (u16*)(ws + 136249344);    //    524,288
  float* cst     = (float*)(ws + 136773632);  //    524,288
  float* att2buf = (float*)(ws + 137297920);  //    524,288
  float* gatebuf = (float*)(ws + 137822208);  //    262,144
  float* bsum    = (float*)(ws + 138084352);  //      8,192
  float* bias_ag = (float*)(ws + 138092544);  //      3,072
  float* bias_fc = (float*)(ws + 138095616);  //     20,224

  cast_k<<<2048, 256, 0, stream>>>(enc, encb);
  prep_k<<<20384, 256, 0, stream>>>(eaw, wih, whh, daw, fbw, fcw, bih, bhh, dab, fbb, fcb,
                                    lens, ea_t, wcat, wag, wfc, bsum, bias_ag, bias_fc, out);
  s1_k<<<256, 256, 0, stream>>>(enc, ihw, ihb, icw, icb, xh, cst);
  // att1 = encoder_out @ enc_att_w + b  -> bf16 [65536 x 512]
  gemm_k<<<dim3(8, 1024), 256, 0, stream>>>(encb, 256, ea_t, 256, eab, 0, 0,
                                            att1, nullptr, nullptr, nullptr, nullptr,
                                            nullptr, nullptr, nullptr);
  // initial att2/gate from h0
  gemm_k<<<dim3(12, 4), 256, 0, stream>>>(xh + 512, 1024, wag, 512, bias_ag, 1, 0,
                                          nullptr, att2buf, gatebuf, nullptr, nullptr,
                                          nullptr, nullptr, nullptr);
  float* alphas_out = out + ALPHA_OFF;
  for (int t = 0; t < Tn; t++) {
    ka_k<<<256, 1024, 0, stream>>>(att1, encb, att2buf, gatebuf, faw, caps, lens, embw,
                                   xh, alphas_out, t);
    gemm_k<<<dim3(32, 4), 256, 0, stream>>>(xh, 1024, wcat, 1024, bsum, 3, t,
                                            nullptr, nullptr, nullptr, nullptr, nullptr,
                                            cst, xh, hall);
    gemm_k<<<dim3(12, 4), 256, 0, stream>>>(xh + 512, 1024, wag, 512, bias_ag, 1, t,
                                            nullptr, att2buf, gatebuf, nullptr, nullptr,
                                            nullptr, nullptr, nullptr);
  }
  // batched preds = hall @ fc_w + fc_b, masked
  gemm_k<<<dim3(79, 384), 256, 0, stream>>>(hall, 512, wfc, 512, bias_fc, 2, 0,
                                            nullptr, nullptr, nullptr, out, lens,
                                            nullptr, nullptr, nullptr);
}